// Round 2
// baseline (613.664 us; speedup 1.0000x reference)
//
#include <hip/hip_runtime.h>
#include <cmath>

typedef __attribute__((ext_vector_type(8))) short short8;
typedef __attribute__((ext_vector_type(4))) float f32x4;

__device__ inline float bf2f(short s) {
  union { unsigned u; float f; } v; v.u = ((unsigned)(unsigned short)s) << 16; return v.f;
}
__device__ inline short f2bf(float f) {
  union { float f; unsigned u; } v; v.f = f;
  unsigned r = v.u + 0x7fffu + ((v.u >> 16) & 1u);
  return (short)(r >> 16);
}

// ---------------- K1: pool(16) + RMSNorm + gelu ----------------
__global__ __launch_bounds__(256) void k_pool(const float* __restrict__ x,
                                              const float* __restrict__ scale,
                                              short* __restrict__ xp,
                                              short* __restrict__ g) {
  int row = blockIdx.x;            // b*512 + s, 0..1023
  int tid = threadIdx.x;
  const float* xr = x + (size_t)row * (16 * 1536);
  float acc[6];
#pragma unroll
  for (int i = 0; i < 6; i++) acc[i] = 0.f;
  for (int j = 0; j < 16; j++) {
#pragma unroll
    for (int i = 0; i < 6; i++) acc[i] += xr[j * 1536 + i * 256 + tid];
  }
  float ss = 0.f;
#pragma unroll
  for (int i = 0; i < 6; i++) { acc[i] *= (1.f / 16.f); ss += acc[i] * acc[i]; }
#pragma unroll
  for (int off = 32; off > 0; off >>= 1) ss += __shfl_xor(ss, off);
  __shared__ float red[4];
  int w = tid >> 6;
  if ((tid & 63) == 0) red[w] = ss;
  __syncthreads();
  float tot = red[0] + red[1] + red[2] + red[3];
  float rms = rsqrtf(tot / 1536.f + 1e-5f);
#pragma unroll
  for (int i = 0; i < 6; i++) {
    int c = i * 256 + tid;
    float v = acc[i] * rms * scale[c];
    xp[row * 1536 + c] = f2bf(v);
    float u = 0.7978845608028654f * (v + 0.044715f * v * v * v);
    float ge = 0.5f * v * (1.f + tanhf(u));
    g[row * 1536 + c] = f2bf(ge);
  }
}

// ---------------- K2: fp32 -> bf16 transpose (dst[c][r] = src[r][c]) ----------------
__global__ __launch_bounds__(256) void k_transpose(const float* __restrict__ src,
                                                   short* __restrict__ dst, int R, int C) {
  __shared__ float t[32][33];
  int c0 = blockIdx.x * 32, r0 = blockIdx.y * 32;
  int tr = threadIdx.x >> 5, tc = threadIdx.x & 31;
#pragma unroll
  for (int i = 0; i < 4; i++)
    t[tr + i * 8][tc] = src[(size_t)(r0 + tr + i * 8) * C + c0 + tc];
  __syncthreads();
#pragma unroll
  for (int i = 0; i < 4; i++) {
    int c = tr + i * 8;
    dst[(size_t)(c0 + c) * R + r0 + tc] = f2bf(t[tc][c]);
  }
}

// ---------------- K3: pos_encoding = masked sums of w_pos + b_pos ----------------
struct Thr { int t[32]; };
__global__ __launch_bounds__(256) void k_posenc(const float* __restrict__ w_pos,
                                                const float* __restrict__ b_pos,
                                                short* __restrict__ pe, Thr thr) {
  int p = blockIdx.x;                      // 0..1023, rel_pos = p - 512
  int dist = (p >= 512) ? (p - 512) : (512 - p);
  float sgn = (p > 512) ? 1.f : ((p < 512) ? -1.f : 0.f);
  int tid = threadIdx.x;
  float acc[16];
#pragma unroll
  for (int i = 0; i < 16; i++) acc[i] = b_pos[i * 256 + tid];
  for (int j = 0; j < 32; j++) {
    if (dist <= thr.t[j]) {
#pragma unroll
      for (int i = 0; i < 16; i++)
        acc[i] += w_pos[j * 4096 + i * 256 + tid] + sgn * w_pos[(32 + j) * 4096 + i * 256 + tid];
    }
  }
#pragma unroll
  for (int i = 0; i < 16; i++) pe[(size_t)p * 4096 + i * 256 + tid] = f2bf(acc[i]);
}

// ---------------- K4: GEMM C[M][N] = A[M][K] @ Bt[N][K]^T (bf16 in, bf16/f32 out) ----
template <int STORE_BF16>
__global__ __launch_bounds__(256, 2) void k_gemm(const short* __restrict__ A,
                                                 const short* __restrict__ B,
                                                 void* __restrict__ Cout,
                                                 int M, int N, int K) {
  __shared__ __align__(16) short As[2][128 * 64];
  __shared__ __align__(16) short Bs[2][128 * 64];
  int bm = blockIdx.x, bn = blockIdx.y;
  int tid = threadIdx.x;
  int l = tid & 63, w = tid >> 6;
  int wm = (w >> 1) * 64, wn = (w & 1) * 64;
  int lr = l & 15, lg = l >> 4;
  f32x4 acc[4][4] = {};
  int nt = K >> 6;
  short8 ra[4], rb[4];

  // prologue: stage tile 0
  {
#pragma unroll
    for (int i = 0; i < 4; i++) {
      int slot = i * 256 + tid;
      int r = slot >> 3, ch = slot & 7;
      ra[i] = *reinterpret_cast<const short8*>(A + (size_t)(bm * 128 + r) * K + ch * 8);
      rb[i] = *reinterpret_cast<const short8*>(B + (size_t)(bn * 128 + r) * K + ch * 8);
    }
#pragma unroll
    for (int i = 0; i < 4; i++) {
      int slot = i * 256 + tid;
      int r = slot >> 3, ch = slot & 7;
      int sw = ch ^ (r & 7);
      *reinterpret_cast<short8*>(&As[0][r * 64 + sw * 8]) = ra[i];
      *reinterpret_cast<short8*>(&Bs[0][r * 64 + sw * 8]) = rb[i];
    }
  }
  __syncthreads();

  for (int t = 0; t < nt; t++) {
    int cur = t & 1;
    if (t + 1 < nt) {
      size_t kb = (size_t)(t + 1) * 64;
#pragma unroll
      for (int i = 0; i < 4; i++) {
        int slot = i * 256 + tid;
        int r = slot >> 3, ch = slot & 7;
        ra[i] = *reinterpret_cast<const short8*>(A + (size_t)(bm * 128 + r) * K + kb + ch * 8);
        rb[i] = *reinterpret_cast<const short8*>(B + (size_t)(bn * 128 + r) * K + kb + ch * 8);
      }
    }
#pragma unroll
    for (int kk = 0; kk < 2; kk++) {
      short8 af[4], bf[4];
#pragma unroll
      for (int m = 0; m < 4; m++) {
        int r = wm + m * 16 + lr;
        int ch = kk * 4 + lg;
        af[m] = *reinterpret_cast<const short8*>(&As[cur][r * 64 + (ch ^ (r & 7)) * 8]);
      }
#pragma unroll
      for (int n = 0; n < 4; n++) {
        int r = wn + n * 16 + lr;
        int ch = kk * 4 + lg;
        bf[n] = *reinterpret_cast<const short8*>(&Bs[cur][r * 64 + (ch ^ (r & 7)) * 8]);
      }
#pragma unroll
      for (int m = 0; m < 4; m++)
#pragma unroll
        for (int n = 0; n < 4; n++)
          acc[m][n] = __builtin_amdgcn_mfma_f32_16x16x32_bf16(af[m], bf[n], acc[m][n], 0, 0, 0);
    }
    __syncthreads();
    if (t + 1 < nt) {
#pragma unroll
      for (int i = 0; i < 4; i++) {
        int slot = i * 256 + tid;
        int r = slot >> 3, ch = slot & 7;
        int sw = ch ^ (r & 7);
        *reinterpret_cast<short8*>(&As[cur ^ 1][r * 64 + sw * 8]) = ra[i];
        *reinterpret_cast<short8*>(&Bs[cur ^ 1][r * 64 + sw * 8]) = rb[i];
      }
    }
    __syncthreads();
  }

#pragma unroll
  for (int m = 0; m < 4; m++)
#pragma unroll
    for (int n = 0; n < 4; n++)
#pragma unroll
      for (int r = 0; r < 4; r++) {
        int row = bm * 128 + wm + m * 16 + lg * 4 + r;
        int col = bn * 128 + wn + n * 16 + lr;
        float v = acc[m][n][r];
        if (STORE_BF16) ((short*)Cout)[(size_t)row * N + col] = f2bf(v);
        else            ((float*)Cout)[(size_t)row * N + col] = v;
      }
}

// ---------------- K5: relative-position diagonal bands ----------------
// which=0: rq2[b][q][h][k] = (q+q_r_bias)·pe[512+k-q]
// which=1: rk2[b][k][h][q] = (k+k_r_bias)·pe[512+q-k]
__global__ __launch_bounds__(64) void k_rel(const short* __restrict__ qk,
                                            const short* __restrict__ pe,
                                            const float* __restrict__ q_r_bias,
                                            const float* __restrict__ k_r_bias,
                                            short* __restrict__ rq2,
                                            short* __restrict__ rk2) {
  int bid = blockIdx.x;
  int which = bid & 1;
  int t16 = (bid >> 1) & 31;
  int h = (bid >> 6) & 31;
  int b = bid >> 11;
  int l = threadIdx.x;
  int lr = l & 15, lg = l >> 4;
  int r0 = t16 * 16;
  int pbase = 497 - r0;   // p = pbase + j,  j = col index in band
  const float* bias = which ? k_r_bias : q_r_bias;
  int colbase = which ? 4096 : 0;
  short* outp = which ? rk2 : rq2;

  short8 af[4];
#pragma unroll
  for (int kk = 0; kk < 4; kk++) {
    int c = kk * 32 + lg * 8;
    short8 v = *reinterpret_cast<const short8*>(
        qk + (size_t)(b * 512 + r0 + lr) * 8192 + colbase + h * 128 + c);
    const float4* bp = reinterpret_cast<const float4*>(bias + h * 128 + c);
    float4 b0 = bp[0], b1 = bp[1];
    short8 o;
    o[0] = f2bf(bf2f(v[0]) + b0.x); o[1] = f2bf(bf2f(v[1]) + b0.y);
    o[2] = f2bf(bf2f(v[2]) + b0.z); o[3] = f2bf(bf2f(v[3]) + b0.w);
    o[4] = f2bf(bf2f(v[4]) + b1.x); o[5] = f2bf(bf2f(v[5]) + b1.y);
    o[6] = f2bf(bf2f(v[6]) + b1.z); o[7] = f2bf(bf2f(v[7]) + b1.w);
    af[kk] = o;
  }

  for (int ct = 0; ct < 33; ct++) {
    int p = pbase + ct * 16 + lr;
    if (p > 1023) p = 1023;
    f32x4 acc = {};
#pragma unroll
    for (int kk = 0; kk < 4; kk++) {
      short8 bf = *reinterpret_cast<const short8*>(
          pe + (size_t)p * 4096 + h * 128 + kk * 32 + lg * 8);
      acc = __builtin_amdgcn_mfma_f32_16x16x32_bf16(af[kk], bf, acc, 0, 0, 0);
    }
#pragma unroll
    for (int reg = 0; reg < 4; reg++) {
      int r = lg * 4 + reg;
      int j = ct * 16 + lr;
      int k = j - 15 + r;
      if (k >= 0 && k < 512)
        outp[((size_t)(b * 512 + r0 + r) * 32 + h) * 512 + k] = f2bf(acc[reg]);
    }
  }
}

// ---------------- K6: fused scores + pair contraction + epilogue ----------------
__global__ __launch_bounds__(256, 2) void k_score(const short* __restrict__ qk,
                                                  const short* __restrict__ rq2,
                                                  const short* __restrict__ rk2,
                                                  const short* __restrict__ wpT,
                                                  const float* __restrict__ b_pair,
                                                  const float* __restrict__ y,
                                                  float* __restrict__ out) {
  __shared__ __align__(16) short a_lds[1024 * 32];
  int qt = blockIdx.x, kt = blockIdx.y, b = blockIdx.z;
  int q0 = qt * 32, k0 = kt * 32;
  int tid = threadIdx.x;
  int l = tid & 63, w = tid >> 6;
  int lr = l & 15, lg = l >> 4;

  // phase 1: per-h A1 = q·k^T plus rel terms -> a_lds[(ql*32+kl)][h] (bf16)
  for (int hh = 0; hh < 8; hh++) {
    int h = w + hh * 4;
    f32x4 acc[2][2] = {};
#pragma unroll
    for (int kk = 0; kk < 4; kk++) {
      short8 af[2], bf[2];
#pragma unroll
      for (int m = 0; m < 2; m++)
        af[m] = *reinterpret_cast<const short8*>(
            qk + (size_t)(b * 512 + q0 + m * 16 + lr) * 8192 + h * 128 + kk * 32 + lg * 8);
#pragma unroll
      for (int n = 0; n < 2; n++)
        bf[n] = *reinterpret_cast<const short8*>(
            qk + (size_t)(b * 512 + k0 + n * 16 + lr) * 8192 + 4096 + h * 128 + kk * 32 + lg * 8);
#pragma unroll
      for (int m = 0; m < 2; m++)
#pragma unroll
        for (int n = 0; n < 2; n++)
          acc[m][n] = __builtin_amdgcn_mfma_f32_16x16x32_bf16(af[m], bf[n], acc[m][n], 0, 0, 0);
    }
#pragma unroll
    for (int m = 0; m < 2; m++)
#pragma unroll
      for (int n = 0; n < 2; n++)
#pragma unroll
        for (int reg = 0; reg < 4; reg++) {
          int ql = m * 16 + lg * 4 + reg;
          int kl = n * 16 + lr;
          int qg = q0 + ql, kg = k0 + kl;
          float rel = 0.5f * (bf2f(rq2[((size_t)(b * 512 + qg) * 32 + h) * 512 + kg]) +
                              bf2f(rk2[((size_t)(b * 512 + kg) * 32 + h) * 512 + qg]));
          a_lds[(ql * 32 + kl) * 32 + h] = f2bf(acc[m][n][reg] + rel);
        }
  }
  __syncthreads();

  // phase 2: (1024 x 32) @ (32 x 128) + b_pair + y_q + y_k
  short8 bfr[8];
#pragma unroll
  for (int n = 0; n < 8; n++)
    bfr[n] = *reinterpret_cast<const short8*>(wpT + (n * 16 + lr) * 32 + lg * 8);
  float bp[8];
#pragma unroll
  for (int n = 0; n < 8; n++) bp[n] = b_pair[n * 16 + lr];

  int rowb = w * 256;
  const f32x4 fz = {};
  for (int m = 0; m < 16; m++) {
    short8 af = *reinterpret_cast<const short8*>(&a_lds[(rowb + m * 16 + lr) * 32 + lg * 8]);
#pragma unroll
    for (int n = 0; n < 8; n++) {
      f32x4 d = __builtin_amdgcn_mfma_f32_16x16x32_bf16(af, bfr[n], fz, 0, 0, 0);
#pragma unroll
      for (int reg = 0; reg < 4; reg++) {
        int row = rowb + m * 16 + lg * 4 + reg;
        int ql = row >> 5, kl = row & 31;
        int qg = q0 + ql, kg = k0 + kl;
        int f = n * 16 + lr;
        float v = d[reg] + bp[n] + y[(size_t)(b * 512 + qg) * 256 + f] +
                  y[(size_t)(b * 512 + kg) * 256 + 128 + f];
        out[((size_t)(b * 512 + qg) * 512 + kg) * 128 + f] = v;
      }
    }
  }
}

// ---------------- launch ----------------
extern "C" void kernel_launch(void* const* d_in, const int* in_sizes, int n_in,
                              void* d_out, int out_size, void* d_ws, size_t ws_size,
                              hipStream_t stream) {
  const float* x        = (const float*)d_in[0];
  const float* scale    = (const float*)d_in[1];
  const float* w_q      = (const float*)d_in[2];
  const float* w_k      = (const float*)d_in[3];
  const float* w_pos    = (const float*)d_in[4];
  const float* b_pos    = (const float*)d_in[5];
  const float* q_r_bias = (const float*)d_in[6];
  const float* k_r_bias = (const float*)d_in[7];
  const float* w_yq     = (const float*)d_in[8];
  const float* w_yk     = (const float*)d_in[9];
  const float* w_pair   = (const float*)d_in[10];
  const float* b_pair   = (const float*)d_in[11];
  float* out = (float*)d_out;

  char* ws = (char*)d_ws;
  size_t off = 0;
  auto alloc = [&](size_t bytes) -> void* {
    void* p = ws + off; off += (bytes + 255) & ~(size_t)255; return p;
  };
  short* xp   = (short*)alloc((size_t)1024 * 1536 * 2);
  short* g    = (short*)alloc((size_t)1024 * 1536 * 2);
  short* wqkT = (short*)alloc((size_t)8192 * 1536 * 2);
  short* wyT  = (short*)alloc((size_t)256 * 1536 * 2);
  short* wpT  = (short*)alloc((size_t)128 * 32 * 2);
  short* pe   = (short*)alloc((size_t)1024 * 4096 * 2);
  short* qk   = (short*)alloc((size_t)1024 * 8192 * 2);
  float* y    = (float*)alloc((size_t)1024 * 256 * 4);
  short* rq2  = (short*)alloc((size_t)2 * 512 * 32 * 512 * 2);
  short* rk2  = (short*)alloc((size_t)2 * 512 * 32 * 512 * 2);
  if (off > ws_size) return;  // workspace too small -> fail loudly (poisoned out)

  Thr thr;
  for (int j = 0; j < 32; j++) {
    double cw = (double)j + pow(481.0, (double)j / 32.0);
    thr.t[j] = (int)ceil(cw) - 1;
  }

  k_pool<<<1024, 256, 0, stream>>>(x, scale, xp, g);
  k_transpose<<<dim3(128, 48), 256, 0, stream>>>(w_q, wqkT, 1536, 4096);
  k_transpose<<<dim3(128, 48), 256, 0, stream>>>(w_k, wqkT + (size_t)4096 * 1536, 1536, 4096);
  k_transpose<<<dim3(4, 48), 256, 0, stream>>>(w_yq, wyT, 1536, 128);
  k_transpose<<<dim3(4, 48), 256, 0, stream>>>(w_yk, wyT + (size_t)128 * 1536, 1536, 128);
  k_transpose<<<dim3(4, 1), 256, 0, stream>>>(w_pair, wpT, 32, 128);
  k_posenc<<<1024, 256, 0, stream>>>(w_pos, b_pos, pe, thr);
  k_gemm<1><<<dim3(8, 64), 256, 0, stream>>>(xp, wqkT, qk, 1024, 8192, 1536);
  k_gemm<0><<<dim3(8, 2), 256, 0, stream>>>(g, wyT, y, 1024, 256, 1536);
  k_rel<<<4096, 64, 0, stream>>>(qk, pe, q_r_bias, k_r_bias, rq2, rk2);
  k_score<<<dim3(16, 16, 2), 256, 0, stream>>>(qk, rq2, rk2, wpT, b_pair, y, out);
}